// Round 9
// baseline (264.429 us; speedup 1.0000x reference)
//
#include <hip/hip_runtime.h>

#define B_  16
#define L_  1024
#define E_  256
#define H_  8
#define DH_ 32
#define M_  (B_ * L_)                 // 16384 rows
#define SCALE_L2E 0.25501817656f      // (1/sqrt(32)) * log2(e)

typedef unsigned short u16;
typedef unsigned int   u32;
typedef short bf8_t __attribute__((ext_vector_type(8)));   // 8 bf16 (4 VGPRs)
typedef float f4_t  __attribute__((ext_vector_type(4)));   // MFMA acc
union F4U { uint4 u; bf8_t s; };

static __device__ __forceinline__ float bf2f(u16 u) {
    return __uint_as_float(((u32)u) << 16);
}
static __device__ __forceinline__ u16 f2bf(float f) {
    u32 u = __float_as_uint(f);
    u32 r = 0x7FFFu + ((u >> 16) & 1u);   // RNE
    return (u16)((u + r) >> 16);
}
static __device__ __forceinline__ u32 pack2(float a, float b) {
    return (u32)f2bf(a) | ((u32)f2bf(b) << 16);
}
// truncated bf16 pair pack: 2 VALU ops (hot-loop only; P values)
static __device__ __forceinline__ u32 pack2t(float a, float b) {
    return (__float_as_uint(a) >> 16) | (__float_as_uint(b) & 0xFFFF0000u);
}

// ---- kernel 1: embedding gather + LN (wave-per-row); low blocks convert W->bf16
__global__ __launch_bounds__(256) void embed_conv_k(
    const int* __restrict__ seq,
    const float* __restrict__ emb_w,      // [L,E,4] fp32 (read as float4)
    const float* __restrict__ emb_b,      // [L,E]
    const float* __restrict__ in_proj_w,  // [768,256] fp32
    const float* __restrict__ out_w,      // [256,256] fp32
    u16* __restrict__ emb,                // [M,256] bf16
    u16* __restrict__ wcvt)               // [768*256 + 256*256] bf16 (wqkv|wout)
{
    int blk = blockIdx.x, tid = threadIdx.x;
    if (blk < 1024) {                      // 262144 weight elements
        int idx = blk * 256 + tid;
        float v = (idx < 196608) ? in_proj_w[idx] : out_w[idx - 196608];
        wcvt[idx] = f2bf(v);
    }
    int w = tid >> 6, lane = tid & 63;
    int bl = blk * 4 + w;                  // row in [0, M)
    int l = bl & (L_ - 1);
    int cls = seq[bl];
    const float4* wrow = (const float4*)emb_w + (size_t)l * 256;
    float4 bb = *(const float4*)(emb_b + (size_t)l * 256 + lane * 4);
    float bv[4] = {bb.x, bb.y, bb.z, bb.w};
    float x[4], s = 0.f, q = 0.f;
    #pragma unroll
    for (int j = 0; j < 4; ++j) {
        float4 w4 = wrow[lane * 4 + j];
        float t = ((cls == 0) ? w4.x : (cls == 1) ? w4.y : (cls == 2) ? w4.z : w4.w) + bv[j];
        x[j] = t; s += t; q += t * t;
    }
    #pragma unroll
    for (int off = 1; off < 64; off <<= 1) {
        s += __shfl_xor(s, off);
        q += __shfl_xor(q, off);
    }
    float mean = s * (1.0f / 256.0f);
    float var  = q * (1.0f / 256.0f) - mean * mean;
    float rstd = rsqrtf(var + 1e-5f);
    ushort4 o = { f2bf((x[0] - mean) * rstd), f2bf((x[1] - mean) * rstd),
                  f2bf((x[2] - mean) * rstd), f2bf((x[3] - mean) * rstd) };
    *(ushort4*)(emb + (size_t)bl * 256 + lane * 4) = o;
}

// ---- kernel 2: QKV = emb @ Wqkv^T + b (MFMA, LDS-free).
// Q/K blocks compute C^T (A=W, B=emb) so each lane holds 4 consecutive d for one
// l -> ushort4 stores into [bh][l][32]. V blocks keep normal orientation and
// store transposed vt[bh][d][l] (ushort4 along l). Q pre-scaled by SCALE*log2e.
__global__ __launch_bounds__(256) void gemm_qkv_mfma_k(
    const u16* __restrict__ emb,      // [M,256] bf16
    const u16* __restrict__ wqkv,     // [768,256] bf16
    const float* __restrict__ bias,   // [768] fp32
    u16* __restrict__ q_s, u16* __restrict__ k_s, u16* __restrict__ vt)
{
    int tid = threadIdx.x;
    int w = tid >> 6, lane = tid & 63, l15 = lane & 15, quad = lane >> 4;
    int n0 = blockIdx.x * 64, m0 = blockIdx.y * 64;
    int b = m0 >> 10;

    const u16* Ap = emb  + (size_t)(m0 + w * 16 + l15) * 256 + quad * 8;
    const u16* Bp = wqkv + (size_t)(n0 + l15) * 256 + quad * 8;

    f4_t acc[4] = {{0,0,0,0},{0,0,0,0},{0,0,0,0},{0,0,0,0}};

    if (n0 < 512) {                        // ---- Q or K: transposed C ----
        #pragma unroll
        for (int ks = 0; ks < 8; ++ks) {
            F4U a; a.u = *(const uint4*)(Ap + ks * 32);
            #pragma unroll
            for (int nc = 0; nc < 4; ++nc) {
                F4U bf; bf.u = *(const uint4*)(Bp + nc * 16 * 256 + ks * 32);
                acc[nc] = __builtin_amdgcn_mfma_f32_16x16x32_bf16(bf.s, a.s, acc[nc], 0, 0, 0);
            }
        }
        int l = (m0 & 1023) + w * 16 + l15;
        float sc = (n0 < 256) ? SCALE_L2E : 1.0f;
        u16* dst = (n0 < 256) ? q_s : k_s;
        #pragma unroll
        for (int nc = 0; nc < 4; ++nc) {
            int nb = n0 + nc * 16 + quad * 4;      // 4 consecutive n = same head
            float4 b4 = *(const float4*)(bias + nb);
            int nl = nb & 255, h = nl >> 5, d0 = nl & 31;
            ushort4 o = { f2bf((acc[nc][0] + b4.x) * sc), f2bf((acc[nc][1] + b4.y) * sc),
                          f2bf((acc[nc][2] + b4.z) * sc), f2bf((acc[nc][3] + b4.w) * sc) };
            *(ushort4*)(dst + ((size_t)(b * 8 + h) * 1024 + l) * 32 + d0) = o;
        }
    } else {                               // ---- V: normal C, store transposed ----
        #pragma unroll
        for (int ks = 0; ks < 8; ++ks) {
            F4U a; a.u = *(const uint4*)(Ap + ks * 32);
            #pragma unroll
            for (int nc = 0; nc < 4; ++nc) {
                F4U bf; bf.u = *(const uint4*)(Bp + nc * 16 * 256 + ks * 32);
                acc[nc] = __builtin_amdgcn_mfma_f32_16x16x32_bf16(a.s, bf.s, acc[nc], 0, 0, 0);
            }
        }
        int lq = (m0 & 1023) + w * 16 + quad * 4;
        #pragma unroll
        for (int nc = 0; nc < 4; ++nc) {
            int n = n0 + nc * 16 + l15;
            float bv = bias[n];
            int nl = n & 255, h = nl >> 5, d = nl & 31;
            ushort4 o = { f2bf(acc[nc][0] + bv), f2bf(acc[nc][1] + bv),
                          f2bf(acc[nc][2] + bv), f2bf(acc[nc][3] + bv) };
            *(ushort4*)(vt + ((size_t)(b * 8 + h) * 32 + d) * 1024 + lq) = o;
        }
    }
}

// ---- kernel 3: MFMA flash attention, fixed-max softmax, barrier-free,
// ping-pong register prefetch, truncated P-pack, PV computed as C[d][q]
// (A=V, B=P -> vectorized ctx stores, no inv broadcast), dual O accumulators.
__global__ __launch_bounds__(256) void attn2_k(
    const u16* __restrict__ q_s,   // [bh][l][32] (pre-scaled by SCALE*log2e)
    const u16* __restrict__ k_s,   // [bh][l][32]
    const u16* __restrict__ vt,    // [bh][32][1024]
    u16* __restrict__ ctx)         // [bh][l][32]
{
    __shared__ u16 Ps[4][16 * 72];     // per-wave P [q][key], stride 72 el
    int tid = threadIdx.x;
    int w = tid >> 6, lane = tid & 63, l15 = lane & 15, quad = lane >> 4;
    int bh = blockIdx.y;
    int q0 = blockIdx.x * 64 + w * 16;

    const u16* kb = k_s + (size_t)bh * 1024 * 32;
    const u16* vb = vt  + (size_t)bh * 32 * 1024;
    u16* psw = Ps[w];

    F4U qf;   // B-frag: lane holds Q[q=l15][d=quad*8+j]
    qf.u = *(const uint4*)(q_s + ((size_t)bh * 1024 + q0 + l15) * 32 + quad * 8);

    f4_t OA0 = {0,0,0,0}, OA1 = {0,0,0,0};   // dual accumulators (A/B steps)
    f4_t OB0 = {0,0,0,0}, OB1 = {0,0,0,0};
    float psum = 0.0f;

    F4U kA[4], vA[4], kB[4], vB[4];

    auto LD = [&](F4U* k, F4U* v, int key0) {
        #pragma unroll
        for (int nt = 0; nt < 4; ++nt)
            k[nt].u = *(const uint4*)(kb + (size_t)(key0 + nt * 16 + l15) * 32 + quad * 8);
        #pragma unroll
        for (int k2 = 0; k2 < 2; ++k2) {
            v[k2 * 2 + 0].u = *(const uint4*)(vb + (size_t)l15 * 1024 + key0 + k2 * 32 + quad * 8);
            v[k2 * 2 + 1].u = *(const uint4*)(vb + (size_t)(16 + l15) * 1024 + key0 + k2 * 32 + quad * 8);
        }
    };
    auto STEP = [&](F4U* k, F4U* v, f4_t& o0, f4_t& o1) {
        f4_t s[4];
        #pragma unroll
        for (int nt = 0; nt < 4; ++nt) {
            f4_t z = {0,0,0,0};
            s[nt] = __builtin_amdgcn_mfma_f32_16x16x32_bf16(k[nt].s, qf.s, z, 0, 0, 0);
        }
        #pragma unroll
        for (int nt = 0; nt < 4; ++nt) {
            float p0 = exp2f(s[nt][0]), p1 = exp2f(s[nt][1]);
            float p2 = exp2f(s[nt][2]), p3 = exp2f(s[nt][3]);
            psum += (p0 + p1) + (p2 + p3);
            uint2 pk = { pack2t(p0, p1), pack2t(p2, p3) };
            *(uint2*)(psw + l15 * 72 + nt * 16 + quad * 4) = pk;
        }
        #pragma unroll
        for (int k2 = 0; k2 < 2; ++k2) {
            F4U pf; pf.u = *(const uint4*)(psw + l15 * 72 + k2 * 32 + quad * 8);
            o0 = __builtin_amdgcn_mfma_f32_16x16x32_bf16(v[k2 * 2 + 0].s, pf.s, o0, 0, 0, 0);
            o1 = __builtin_amdgcn_mfma_f32_16x16x32_bf16(v[k2 * 2 + 1].s, pf.s, o1, 0, 0, 0);
        }
    };

    LD(kA, vA, 0);
    for (int c = 0; c < 16; c += 2) {
        LD(kB, vB, (c + 1) * 64);
        STEP(kA, vA, OA0, OA1);
        if (c + 2 < 16) LD(kA, vA, (c + 2) * 64);
        STEP(kB, vB, OB0, OB1);
    }

    // psum for q=l15: reduce across the 4 quads; every lane then owns its q
    psum += __shfl_xor(psum, 16);
    psum += __shfl_xor(psum, 32);
    float inv = 1.0f / psum;

    // O C-layout is [d=quad*4+r][q=l15]: pack 4 d's -> 8B stores
    u16* op = ctx + ((size_t)bh * 1024 + q0 + l15) * 32;
    uint2 s0 = { pack2(OA0[0] + OB0[0], OA0[1] + OB0[1]) , 0 };
    s0.y = pack2((OA0[2] + OB0[2]), (OA0[3] + OB0[3]));
    uint2 s1 = { pack2(OA1[0] + OB1[0], OA1[1] + OB1[1]),
                 pack2(OA1[2] + OB1[2], OA1[3] + OB1[3]) };
    // apply inv before packing
    s0.x = pack2((OA0[0] + OB0[0]) * inv, (OA0[1] + OB0[1]) * inv);
    s0.y = pack2((OA0[2] + OB0[2]) * inv, (OA0[3] + OB0[3]) * inv);
    s1.x = pack2((OA1[0] + OB1[0]) * inv, (OA1[1] + OB1[1]) * inv);
    s1.y = pack2((OA1[2] + OB1[2]) * inv, (OA1[3] + OB1[3]) * inv);
    *(uint2*)(op + quad * 4)      = s0;
    *(uint2*)(op + 16 + quad * 4) = s1;
}

// ---- kernel 4: out = LN(ctx @ Wout^T + out_b + emb) -> fp32, fused.
// Transposed C (A=W, B=ctx): each lane owns ONE output row (m=l15) with 64
// n-values (nc*16+quad*4+r) -> LN stats need only 2 shfl_xor; float4 stores.
__global__ __launch_bounds__(256) void proj_ln_k(
    const u16* __restrict__ ctx,      // [bh][l][32] bf16
    const u16* __restrict__ wout,     // [256,256] bf16
    const float* __restrict__ out_b,  // [256]
    const u16* __restrict__ emb,      // [M,256] bf16
    float* __restrict__ out)          // [M,256] fp32
{
    int tid = threadIdx.x;
    int w = tid >> 6, lane = tid & 63, l15 = lane & 15, quad = lane >> 4;
    int m0 = blockIdx.x * 64;
    int b = m0 >> 10, lbase = (m0 & 1023) + w * 16 + l15;

    const u16* Bp = wout + (size_t)l15 * 256 + quad * 8;

    f4_t acc[16];
    #pragma unroll
    for (int nc = 0; nc < 16; ++nc) acc[nc] = (f4_t){0,0,0,0};

    #pragma unroll
    for (int ks = 0; ks < 8; ++ks) {      // k = ks*32 + quad*8+j (head ks)
        F4U a; a.u = *(const uint4*)(ctx + ((size_t)(b * 8 + ks) * 1024 + lbase) * 32 + quad * 8);
        #pragma unroll
        for (int nc = 0; nc < 16; ++nc) {
            F4U bf; bf.u = *(const uint4*)(Bp + (size_t)nc * 16 * 256 + ks * 32);
            acc[nc] = __builtin_amdgcn_mfma_f32_16x16x32_bf16(bf.s, a.s, acc[nc], 0, 0, 0);
        }
    }

    int row = m0 + w * 16 + l15;
    float s = 0.f, q = 0.f;
    #pragma unroll
    for (int nc = 0; nc < 16; ++nc) {
        int nb = nc * 16 + quad * 4;
        float4 bb = *(const float4*)(out_b + nb);
        ushort4 e4 = *(const ushort4*)(emb + (size_t)row * 256 + nb);
        acc[nc][0] += bb.x + bf2f(e4.x);
        acc[nc][1] += bb.y + bf2f(e4.y);
        acc[nc][2] += bb.z + bf2f(e4.z);
        acc[nc][3] += bb.w + bf2f(e4.w);
        #pragma unroll
        for (int r = 0; r < 4; ++r) { s += acc[nc][r]; q += acc[nc][r] * acc[nc][r]; }
    }
    s += __shfl_xor(s, 16);  q += __shfl_xor(q, 16);
    s += __shfl_xor(s, 32);  q += __shfl_xor(q, 32);
    float mean = s * (1.0f / 256.0f);
    float var  = q * (1.0f / 256.0f) - mean * mean;
    float rstd = rsqrtf(var + 1e-5f);
    #pragma unroll
    for (int nc = 0; nc < 16; ++nc) {
        float4 o = { (acc[nc][0] - mean) * rstd, (acc[nc][1] - mean) * rstd,
                     (acc[nc][2] - mean) * rstd, (acc[nc][3] - mean) * rstd };
        *(float4*)(out + (size_t)row * 256 + nc * 16 + quad * 4) = o;
    }
}

extern "C" void kernel_launch(void* const* d_in, const int* in_sizes, int n_in,
                              void* d_out, int out_size, void* d_ws, size_t ws_size,
                              hipStream_t stream) {
    const int*   seq       = (const int*)d_in[0];
    const float* emb_w     = (const float*)d_in[1];
    const float* emb_b     = (const float*)d_in[2];
    const float* in_proj_w = (const float*)d_in[3];
    const float* in_proj_b = (const float*)d_in[4];
    const float* out_w     = (const float*)d_in[5];
    const float* out_b     = (const float*)d_in[6];
    float*       out       = (float*)d_out;

    const size_t P = (size_t)M_ * 256;
    u16* ws   = (u16*)d_ws;
    u16* emb  = ws;                 //  8 MB [M,256]
    u16* q_s  = ws + P;             //  8 MB [bh][l][32]
    u16* k_s  = ws + 2 * P;         //  8 MB [bh][l][32]
    u16* vt   = ws + 3 * P;         //  8 MB [bh][32][1024]
    u16* ctx  = ws + 4 * P;         //  8 MB [bh][l][32]
    u16* wqkv = ws + 5 * P;         //  384 KB [768,256] bf16
    u16* wout = wqkv + 768 * 256;   //  128 KB [256,256] bf16

    embed_conv_k<<<M_ / 4, 256, 0, stream>>>(seq, emb_w, emb_b, in_proj_w, out_w, emb, wqkv);
    gemm_qkv_mfma_k<<<dim3(12, 256), 256, 0, stream>>>(emb, wqkv, in_proj_b, q_s, k_s, vt);
    attn2_k<<<dim3(16, 128), 256, 0, stream>>>(q_s, k_s, vt, ctx);
    proj_ln_k<<<M_ / 64, 256, 0, stream>>>(ctx, wout, out_b, emb, out);
}

// Round 10
// 257.871 us; speedup vs baseline: 1.0254x; 1.0254x over previous
//
#include <hip/hip_runtime.h>

#define B_  16
#define L_  1024
#define E_  256
#define H_  8
#define DH_ 32
#define M_  (B_ * L_)                 // 16384 rows
#define SCALE_L2E 0.25501817656f      // (1/sqrt(32)) * log2(e)

typedef unsigned short u16;
typedef unsigned int   u32;
typedef short bf8_t __attribute__((ext_vector_type(8)));   // 8 bf16 (4 VGPRs)
typedef float f4_t  __attribute__((ext_vector_type(4)));   // MFMA acc
union F4U { uint4 u; bf8_t s; };

static __device__ __forceinline__ float bf2f(u16 u) {
    return __uint_as_float(((u32)u) << 16);
}
static __device__ __forceinline__ u16 f2bf(float f) {
    u32 u = __float_as_uint(f);
    u32 r = 0x7FFFu + ((u >> 16) & 1u);   // RNE
    return (u16)((u + r) >> 16);
}
static __device__ __forceinline__ u32 pack2(float a, float b) {
    return (u32)f2bf(a) | ((u32)f2bf(b) << 16);
}
// truncated bf16 pair pack: 2 VALU ops (P values only; psum stays exact fp32)
static __device__ __forceinline__ u32 pack2t(float a, float b) {
    return (__float_as_uint(a) >> 16) | (__float_as_uint(b) & 0xFFFF0000u);
}

// ---- kernel 1: embedding gather + LN (wave-per-row); low blocks convert W->bf16
__global__ __launch_bounds__(256) void embed_conv_k(
    const int* __restrict__ seq,
    const float* __restrict__ emb_w,      // [L,E,4] fp32 (read as float4)
    const float* __restrict__ emb_b,      // [L,E]
    const float* __restrict__ in_proj_w,  // [768,256] fp32
    const float* __restrict__ out_w,      // [256,256] fp32
    u16* __restrict__ emb,                // [M,256] bf16
    u16* __restrict__ wcvt)               // [768*256 + 256*256] bf16 (wqkv|wout)
{
    int blk = blockIdx.x, tid = threadIdx.x;
    if (blk < 1024) {                      // 262144 weight elements
        int idx = blk * 256 + tid;
        float v = (idx < 196608) ? in_proj_w[idx] : out_w[idx - 196608];
        wcvt[idx] = f2bf(v);
    }
    int w = tid >> 6, lane = tid & 63;
    int bl = blk * 4 + w;                  // row in [0, M)
    int l = bl & (L_ - 1);
    int cls = seq[bl];
    const float4* wrow = (const float4*)emb_w + (size_t)l * 256;
    float4 bb = *(const float4*)(emb_b + (size_t)l * 256 + lane * 4);
    float bv[4] = {bb.x, bb.y, bb.z, bb.w};
    float x[4], s = 0.f, q = 0.f;
    #pragma unroll
    for (int j = 0; j < 4; ++j) {
        float4 w4 = wrow[lane * 4 + j];
        float t = ((cls == 0) ? w4.x : (cls == 1) ? w4.y : (cls == 2) ? w4.z : w4.w) + bv[j];
        x[j] = t; s += t; q += t * t;
    }
    #pragma unroll
    for (int off = 1; off < 64; off <<= 1) {
        s += __shfl_xor(s, off);
        q += __shfl_xor(q, off);
    }
    float mean = s * (1.0f / 256.0f);
    float var  = q * (1.0f / 256.0f) - mean * mean;
    float rstd = rsqrtf(var + 1e-5f);
    ushort4 o = { f2bf((x[0] - mean) * rstd), f2bf((x[1] - mean) * rstd),
                  f2bf((x[2] - mean) * rstd), f2bf((x[3] - mean) * rstd) };
    *(ushort4*)(emb + (size_t)bl * 256 + lane * 4) = o;
}

// ---- kernel 2: QKV = emb @ Wqkv^T + b (MFMA, LDS-free).
// Q/K blocks compute C^T (A=W, B=emb) -> ushort4 stores into [bh][l][32];
// V blocks normal C, stored transposed vt[bh][d][l]. Q pre-scaled by SCALE*log2e.
__global__ __launch_bounds__(256) void gemm_qkv_mfma_k(
    const u16* __restrict__ emb,      // [M,256] bf16
    const u16* __restrict__ wqkv,     // [768,256] bf16
    const float* __restrict__ bias,   // [768] fp32
    u16* __restrict__ q_s, u16* __restrict__ k_s, u16* __restrict__ vt)
{
    int tid = threadIdx.x;
    int w = tid >> 6, lane = tid & 63, l15 = lane & 15, quad = lane >> 4;
    int n0 = blockIdx.x * 64, m0 = blockIdx.y * 64;
    int b = m0 >> 10;

    const u16* Ap = emb  + (size_t)(m0 + w * 16 + l15) * 256 + quad * 8;
    const u16* Bp = wqkv + (size_t)(n0 + l15) * 256 + quad * 8;

    f4_t acc[4] = {{0,0,0,0},{0,0,0,0},{0,0,0,0},{0,0,0,0}};

    if (n0 < 512) {                        // ---- Q or K: transposed C ----
        #pragma unroll
        for (int ks = 0; ks < 8; ++ks) {
            F4U a; a.u = *(const uint4*)(Ap + ks * 32);
            #pragma unroll
            for (int nc = 0; nc < 4; ++nc) {
                F4U bf; bf.u = *(const uint4*)(Bp + nc * 16 * 256 + ks * 32);
                acc[nc] = __builtin_amdgcn_mfma_f32_16x16x32_bf16(bf.s, a.s, acc[nc], 0, 0, 0);
            }
        }
        int l = (m0 & 1023) + w * 16 + l15;
        float sc = (n0 < 256) ? SCALE_L2E : 1.0f;
        u16* dst = (n0 < 256) ? q_s : k_s;
        #pragma unroll
        for (int nc = 0; nc < 4; ++nc) {
            int nb = n0 + nc * 16 + quad * 4;      // 4 consecutive n = same head
            float4 b4 = *(const float4*)(bias + nb);
            int nl = nb & 255, h = nl >> 5, d0 = nl & 31;
            ushort4 o = { f2bf((acc[nc][0] + b4.x) * sc), f2bf((acc[nc][1] + b4.y) * sc),
                          f2bf((acc[nc][2] + b4.z) * sc), f2bf((acc[nc][3] + b4.w) * sc) };
            *(ushort4*)(dst + ((size_t)(b * 8 + h) * 1024 + l) * 32 + d0) = o;
        }
    } else {                               // ---- V: normal C, store transposed ----
        #pragma unroll
        for (int ks = 0; ks < 8; ++ks) {
            F4U a; a.u = *(const uint4*)(Ap + ks * 32);
            #pragma unroll
            for (int nc = 0; nc < 4; ++nc) {
                F4U bf; bf.u = *(const uint4*)(Bp + nc * 16 * 256 + ks * 32);
                acc[nc] = __builtin_amdgcn_mfma_f32_16x16x32_bf16(a.s, bf.s, acc[nc], 0, 0, 0);
            }
        }
        int lq = (m0 & 1023) + w * 16 + quad * 4;
        #pragma unroll
        for (int nc = 0; nc < 4; ++nc) {
            int n = n0 + nc * 16 + l15;
            float bv = bias[n];
            int nl = n & 255, h = nl >> 5, d = nl & 31;
            ushort4 o = { f2bf(acc[nc][0] + bv), f2bf(acc[nc][1] + bv),
                          f2bf(acc[nc][2] + bv), f2bf(acc[nc][3] + bv) };
            *(ushort4*)(vt + ((size_t)(b * 8 + h) * 32 + d) * 1024 + lq) = o;
        }
    }
}

// ---- kernel 3: MFMA flash attention. XCD-swizzled 1D grid: all 16 q-tile
// blocks of a bh share g%8 (same XCD) -> per-XCD K/V working set 2 MB (L2-hit).
// K register ping-pong; V loads issued at STEP top (~300 cyc before use).
__global__ __launch_bounds__(256) void attn2_k(
    const u16* __restrict__ q_s,   // [bh][l][32] (pre-scaled by SCALE*log2e)
    const u16* __restrict__ k_s,   // [bh][l][32]
    const u16* __restrict__ vt,    // [bh][32][1024]
    u16* __restrict__ ctx)         // [bh][l][32]
{
    __shared__ u16 Ps[4][16 * 72];     // per-wave P [q][key], stride 72 el
    int tid = threadIdx.x;
    int w = tid >> 6, lane = tid & 63, l15 = lane & 15, quad = lane >> 4;
    int g = blockIdx.x;
    int bh = (g & 7) | ((g >> 7) << 3);       // XCD-local bh grouping
    int q0 = ((g >> 3) & 15) * 64 + w * 16;

    const u16* kb = k_s + (size_t)bh * 1024 * 32;
    const u16* vb = vt  + (size_t)bh * 32 * 1024;
    u16* psw = Ps[w];

    F4U qf;   // B-frag: lane holds Q[q=l15][d=quad*8+j]
    qf.u = *(const uint4*)(q_s + ((size_t)bh * 1024 + q0 + l15) * 32 + quad * 8);

    f4_t OA0 = {0,0,0,0}, OA1 = {0,0,0,0};   // dual accumulators (A/B steps)
    f4_t OB0 = {0,0,0,0}, OB1 = {0,0,0,0};
    float psum = 0.0f;

    F4U kA[4], kB[4];

    auto LDK = [&](F4U* k, int key0) {
        #pragma unroll
        for (int nt = 0; nt < 4; ++nt)
            k[nt].u = *(const uint4*)(kb + (size_t)(key0 + nt * 16 + l15) * 32 + quad * 8);
    };
    auto STEP = [&](F4U* k, int key0, f4_t& o0, f4_t& o1) {
        F4U v[4];   // issue V loads first; consumed after scores+exp+LDS (~300 cyc)
        v[0].u = *(const uint4*)(vb + (size_t)l15 * 1024 + key0 + quad * 8);
        v[1].u = *(const uint4*)(vb + (size_t)(16 + l15) * 1024 + key0 + quad * 8);
        v[2].u = *(const uint4*)(vb + (size_t)l15 * 1024 + key0 + 32 + quad * 8);
        v[3].u = *(const uint4*)(vb + (size_t)(16 + l15) * 1024 + key0 + 32 + quad * 8);
        f4_t s[4];
        #pragma unroll
        for (int nt = 0; nt < 4; ++nt) {
            f4_t z = {0,0,0,0};
            s[nt] = __builtin_amdgcn_mfma_f32_16x16x32_bf16(k[nt].s, qf.s, z, 0, 0, 0);
        }
        #pragma unroll
        for (int nt = 0; nt < 4; ++nt) {
            float p0 = exp2f(s[nt][0]), p1 = exp2f(s[nt][1]);
            float p2 = exp2f(s[nt][2]), p3 = exp2f(s[nt][3]);
            psum += (p0 + p1) + (p2 + p3);
            uint2 pk = { pack2t(p0, p1), pack2t(p2, p3) };
            *(uint2*)(psw + l15 * 72 + nt * 16 + quad * 4) = pk;
        }
        #pragma unroll
        for (int k2 = 0; k2 < 2; ++k2) {
            F4U pf; pf.u = *(const uint4*)(psw + l15 * 72 + k2 * 32 + quad * 8);
            o0 = __builtin_amdgcn_mfma_f32_16x16x32_bf16(v[k2 * 2 + 0].s, pf.s, o0, 0, 0, 0);
            o1 = __builtin_amdgcn_mfma_f32_16x16x32_bf16(v[k2 * 2 + 1].s, pf.s, o1, 0, 0, 0);
        }
    };

    LDK(kA, 0);
    for (int c = 0; c < 16; c += 2) {
        LDK(kB, (c + 1) * 64);
        STEP(kA, c * 64, OA0, OA1);
        if (c + 2 < 16) LDK(kA, (c + 2) * 64);
        STEP(kB, (c + 1) * 64, OB0, OB1);
    }

    // psum for q=l15: reduce across the 4 quads; every lane then owns its q
    psum += __shfl_xor(psum, 16);
    psum += __shfl_xor(psum, 32);
    float inv = 1.0f / psum;

    // O C-layout is [d=quad*4+r][q=l15]: pack 4 d's -> 8B stores
    u16* op = ctx + ((size_t)bh * 1024 + q0 + l15) * 32;
    uint2 s0, s1;
    s0.x = pack2((OA0[0] + OB0[0]) * inv, (OA0[1] + OB0[1]) * inv);
    s0.y = pack2((OA0[2] + OB0[2]) * inv, (OA0[3] + OB0[3]) * inv);
    s1.x = pack2((OA1[0] + OB1[0]) * inv, (OA1[1] + OB1[1]) * inv);
    s1.y = pack2((OA1[2] + OB1[2]) * inv, (OA1[3] + OB1[3]) * inv);
    *(uint2*)(op + quad * 4)      = s0;
    *(uint2*)(op + 16 + quad * 4) = s1;
}

// ---- kernel 4: out = LN(ctx @ Wout^T + out_b + emb) -> fp32, fused.
// 512 blocks x 32 rows; wave (wr,wc): rows wr*16, cols wc*128 (8 nc frags).
// Transposed C: each lane owns one token row's 32 cols; LN = 2 shfl_xor +
// tiny LDS exchange between the two col-half waves.
__global__ __launch_bounds__(256) void proj_ln_k(
    const u16* __restrict__ ctx,      // [bh][l][32] bf16
    const u16* __restrict__ wout,     // [256,256] bf16
    const float* __restrict__ out_b,  // [256]
    const u16* __restrict__ emb,      // [M,256] bf16
    float* __restrict__ out)          // [M,256] fp32
{
    __shared__ float2 sm[2][2][16];   // [wr][wc][l15]
    int tid = threadIdx.x;
    int w = tid >> 6, lane = tid & 63, l15 = lane & 15, quad = lane >> 4;
    int wr = w >> 1, wc = w & 1;
    int m0 = blockIdx.x * 32;
    int b = m0 >> 10, lbase = (m0 & 1023) + wr * 16 + l15;

    const u16* Bp = wout + (size_t)(wc * 128 + l15) * 256 + quad * 8;

    f4_t acc[8];
    #pragma unroll
    for (int nc = 0; nc < 8; ++nc) acc[nc] = (f4_t){0,0,0,0};

    #pragma unroll
    for (int ks = 0; ks < 8; ++ks) {      // k = ks*32 + quad*8+j (head ks)
        F4U a; a.u = *(const uint4*)(ctx + ((size_t)(b * 8 + ks) * 1024 + lbase) * 32 + quad * 8);
        #pragma unroll
        for (int nc = 0; nc < 8; ++nc) {
            F4U bf; bf.u = *(const uint4*)(Bp + (size_t)nc * 16 * 256 + ks * 32);
            acc[nc] = __builtin_amdgcn_mfma_f32_16x16x32_bf16(bf.s, a.s, acc[nc], 0, 0, 0);
        }
    }

    int row = m0 + wr * 16 + l15;
    float s = 0.f, q = 0.f;
    #pragma unroll
    for (int nc = 0; nc < 8; ++nc) {
        int nb = wc * 128 + nc * 16 + quad * 4;
        float4 bb = *(const float4*)(out_b + nb);
        ushort4 e4 = *(const ushort4*)(emb + (size_t)row * 256 + nb);
        acc[nc][0] += bb.x + bf2f(e4.x);
        acc[nc][1] += bb.y + bf2f(e4.y);
        acc[nc][2] += bb.z + bf2f(e4.z);
        acc[nc][3] += bb.w + bf2f(e4.w);
        #pragma unroll
        for (int r = 0; r < 4; ++r) { s += acc[nc][r]; q += acc[nc][r] * acc[nc][r]; }
    }
    s += __shfl_xor(s, 16);  q += __shfl_xor(q, 16);
    s += __shfl_xor(s, 32);  q += __shfl_xor(q, 32);
    if (quad == 0) sm[wr][wc][l15] = make_float2(s, q);
    __syncthreads();
    float2 oth = sm[wr][1 - wc][l15];
    s += oth.x; q += oth.y;
    float mean = s * (1.0f / 256.0f);
    float var  = q * (1.0f / 256.0f) - mean * mean;
    float rstd = rsqrtf(var + 1e-5f);
    #pragma unroll
    for (int nc = 0; nc < 8; ++nc) {
        float4 o = { (acc[nc][0] - mean) * rstd, (acc[nc][1] - mean) * rstd,
                     (acc[nc][2] - mean) * rstd, (acc[nc][3] - mean) * rstd };
        *(float4*)(out + (size_t)row * 256 + wc * 128 + nc * 16 + quad * 4) = o;
    }
}

extern "C" void kernel_launch(void* const* d_in, const int* in_sizes, int n_in,
                              void* d_out, int out_size, void* d_ws, size_t ws_size,
                              hipStream_t stream) {
    const int*   seq       = (const int*)d_in[0];
    const float* emb_w     = (const float*)d_in[1];
    const float* emb_b     = (const float*)d_in[2];
    const float* in_proj_w = (const float*)d_in[3];
    const float* in_proj_b = (const float*)d_in[4];
    const float* out_w     = (const float*)d_in[5];
    const float* out_b     = (const float*)d_in[6];
    float*       out       = (float*)d_out;

    const size_t P = (size_t)M_ * 256;
    u16* ws   = (u16*)d_ws;
    u16* emb  = ws;                 //  8 MB [M,256]
    u16* q_s  = ws + P;             //  8 MB [bh][l][32]
    u16* k_s  = ws + 2 * P;         //  8 MB [bh][l][32]
    u16* vt   = ws + 3 * P;         //  8 MB [bh][32][1024]
    u16* ctx  = ws + 4 * P;         //  8 MB [bh][l][32]
    u16* wqkv = ws + 5 * P;         //  384 KB [768,256] bf16
    u16* wout = wqkv + 768 * 256;   //  128 KB [256,256] bf16

    embed_conv_k<<<M_ / 4, 256, 0, stream>>>(seq, emb_w, emb_b, in_proj_w, out_w, emb, wqkv);
    gemm_qkv_mfma_k<<<dim3(12, 256), 256, 0, stream>>>(emb, wqkv, in_proj_b, q_s, k_s, vt);
    attn2_k<<<2048, 256, 0, stream>>>(q_s, k_s, vt, ctx);
    proj_ln_k<<<M_ / 32, 256, 0, stream>>>(ctx, wout, out_b, emb, out);
}

// Round 11
// 199.196 us; speedup vs baseline: 1.3275x; 1.2946x over previous
//
#include <hip/hip_runtime.h>

#define B_  16
#define L_  1024
#define E_  256
#define H_  8
#define DH_ 32
#define M_  (B_ * L_)                 // 16384 rows
#define SCALE_L2E 0.25501817656f      // (1/sqrt(32)) * log2(e)

typedef unsigned short u16;
typedef unsigned int   u32;
typedef short bf8_t __attribute__((ext_vector_type(8)));   // 8 bf16 (4 VGPRs)
typedef float f4_t  __attribute__((ext_vector_type(4)));   // MFMA acc
union F4U { uint4 u; bf8_t s; };

static __device__ __forceinline__ float bf2f(u16 u) {
    return __uint_as_float(((u32)u) << 16);
}
static __device__ __forceinline__ u16 f2bf(float f) {
    u32 u = __float_as_uint(f);
    u32 r = 0x7FFFu + ((u >> 16) & 1u);   // RNE
    return (u16)((u + r) >> 16);
}
static __device__ __forceinline__ u32 pack2(float a, float b) {
    return (u32)f2bf(a) | ((u32)f2bf(b) << 16);
}
// truncated bf16 pair pack: 2 VALU ops (P values only; psum stays exact fp32)
static __device__ __forceinline__ u32 pack2t(float a, float b) {
    return (__float_as_uint(a) >> 16) | (__float_as_uint(b) & 0xFFFF0000u);
}

// ---- kernel 1: embedding gather + LN (wave-per-row); low blocks convert W->bf16
__global__ __launch_bounds__(256) void embed_conv_k(
    const int* __restrict__ seq,
    const float* __restrict__ emb_w,      // [L,E,4] fp32 (read as float4)
    const float* __restrict__ emb_b,      // [L,E]
    const float* __restrict__ in_proj_w,  // [768,256] fp32
    const float* __restrict__ out_w,      // [256,256] fp32
    u16* __restrict__ emb,                // [M,256] bf16
    u16* __restrict__ wcvt)               // [768*256 + 256*256] bf16 (wqkv|wout)
{
    int blk = blockIdx.x, tid = threadIdx.x;
    if (blk < 1024) {                      // 262144 weight elements
        int idx = blk * 256 + tid;
        float v = (idx < 196608) ? in_proj_w[idx] : out_w[idx - 196608];
        wcvt[idx] = f2bf(v);
    }
    int w = tid >> 6, lane = tid & 63;
    int bl = blk * 4 + w;                  // row in [0, M)
    int l = bl & (L_ - 1);
    int cls = seq[bl];
    const float4* wrow = (const float4*)emb_w + (size_t)l * 256;
    float4 bb = *(const float4*)(emb_b + (size_t)l * 256 + lane * 4);
    float bv[4] = {bb.x, bb.y, bb.z, bb.w};
    float x[4], s = 0.f, q = 0.f;
    #pragma unroll
    for (int j = 0; j < 4; ++j) {
        float4 w4 = wrow[lane * 4 + j];
        float t = ((cls == 0) ? w4.x : (cls == 1) ? w4.y : (cls == 2) ? w4.z : w4.w) + bv[j];
        x[j] = t; s += t; q += t * t;
    }
    #pragma unroll
    for (int off = 1; off < 64; off <<= 1) {
        s += __shfl_xor(s, off);
        q += __shfl_xor(q, off);
    }
    float mean = s * (1.0f / 256.0f);
    float var  = q * (1.0f / 256.0f) - mean * mean;
    float rstd = rsqrtf(var + 1e-5f);
    ushort4 o = { f2bf((x[0] - mean) * rstd), f2bf((x[1] - mean) * rstd),
                  f2bf((x[2] - mean) * rstd), f2bf((x[3] - mean) * rstd) };
    *(ushort4*)(emb + (size_t)bl * 256 + lane * 4) = o;
}

// ---- kernel 2: QKV = emb @ Wqkv^T + b (MFMA, LDS-free), 2 m-tiles per wave
// (B-frags reused -> weight traffic halved). Q/K: transposed C -> ushort4
// stores into [bh][l][32]; V: normal C, stored transposed vt[bh][d][l].
__global__ __launch_bounds__(256) void gemm_qkv_mfma_k(
    const u16* __restrict__ emb,      // [M,256] bf16
    const u16* __restrict__ wqkv,     // [768,256] bf16
    const float* __restrict__ bias,   // [768] fp32
    u16* __restrict__ q_s, u16* __restrict__ k_s, u16* __restrict__ vt)
{
    int tid = threadIdx.x;
    int w = tid >> 6, lane = tid & 63, l15 = lane & 15, quad = lane >> 4;
    int n0 = blockIdx.x * 64, m0 = blockIdx.y * 128;
    int b = m0 >> 10;

    const u16* Ap0 = emb  + (size_t)(m0 + w * 32 + l15) * 256 + quad * 8;
    const u16* Ap1 = Ap0 + 16 * 256;
    const u16* Bp  = wqkv + (size_t)(n0 + l15) * 256 + quad * 8;

    f4_t acc[2][4] = {{{0,0,0,0},{0,0,0,0},{0,0,0,0},{0,0,0,0}},
                      {{0,0,0,0},{0,0,0,0},{0,0,0,0},{0,0,0,0}}};

    if (n0 < 512) {                        // ---- Q or K: transposed C ----
        #pragma unroll
        for (int ks = 0; ks < 8; ++ks) {
            F4U a0, a1;
            a0.u = *(const uint4*)(Ap0 + ks * 32);
            a1.u = *(const uint4*)(Ap1 + ks * 32);
            #pragma unroll
            for (int nc = 0; nc < 4; ++nc) {
                F4U bf; bf.u = *(const uint4*)(Bp + nc * 16 * 256 + ks * 32);
                acc[0][nc] = __builtin_amdgcn_mfma_f32_16x16x32_bf16(bf.s, a0.s, acc[0][nc], 0, 0, 0);
                acc[1][nc] = __builtin_amdgcn_mfma_f32_16x16x32_bf16(bf.s, a1.s, acc[1][nc], 0, 0, 0);
            }
        }
        float sc = (n0 < 256) ? SCALE_L2E : 1.0f;
        u16* dst = (n0 < 256) ? q_s : k_s;
        #pragma unroll
        for (int t = 0; t < 2; ++t) {
            int l = (m0 & 1023) + w * 32 + t * 16 + l15;
            #pragma unroll
            for (int nc = 0; nc < 4; ++nc) {
                int nb = n0 + nc * 16 + quad * 4;  // 4 consecutive n = same head
                float4 b4 = *(const float4*)(bias + nb);
                int nl = nb & 255, h = nl >> 5, d0 = nl & 31;
                ushort4 o = { f2bf((acc[t][nc][0] + b4.x) * sc), f2bf((acc[t][nc][1] + b4.y) * sc),
                              f2bf((acc[t][nc][2] + b4.z) * sc), f2bf((acc[t][nc][3] + b4.w) * sc) };
                *(ushort4*)(dst + ((size_t)(b * 8 + h) * 1024 + l) * 32 + d0) = o;
            }
        }
    } else {                               // ---- V: normal C, store transposed ----
        #pragma unroll
        for (int ks = 0; ks < 8; ++ks) {
            F4U a0, a1;
            a0.u = *(const uint4*)(Ap0 + ks * 32);
            a1.u = *(const uint4*)(Ap1 + ks * 32);
            #pragma unroll
            for (int nc = 0; nc < 4; ++nc) {
                F4U bf; bf.u = *(const uint4*)(Bp + nc * 16 * 256 + ks * 32);
                acc[0][nc] = __builtin_amdgcn_mfma_f32_16x16x32_bf16(a0.s, bf.s, acc[0][nc], 0, 0, 0);
                acc[1][nc] = __builtin_amdgcn_mfma_f32_16x16x32_bf16(a1.s, bf.s, acc[1][nc], 0, 0, 0);
            }
        }
        #pragma unroll
        for (int t = 0; t < 2; ++t) {
            int lq = (m0 & 1023) + w * 32 + t * 16 + quad * 4;
            #pragma unroll
            for (int nc = 0; nc < 4; ++nc) {
                int n = n0 + nc * 16 + l15;
                float bv = bias[n];
                int nl = n & 255, h = nl >> 5, d = nl & 31;
                ushort4 o = { f2bf(acc[t][nc][0] + bv), f2bf(acc[t][nc][1] + bv),
                              f2bf(acc[t][nc][2] + bv), f2bf(acc[t][nc][3] + bv) };
                *(ushort4*)(vt + ((size_t)(b * 8 + h) * 32 + d) * 1024 + lq) = o;
            }
        }
    }
}

// ---- kernel 3: MFMA flash attention. 32 q-rows per wave (2 q-tiles share all
// K/V fragments -> 2x arithmetic intensity, intra-wave ILP). XCD-swizzled:
// all 8 blocks of a bh share g%8. K ping-pong prefetch; fixed-max softmax.
__global__ __launch_bounds__(256) void attn2_k(
    const u16* __restrict__ q_s,   // [bh][l][32] (pre-scaled by SCALE*log2e)
    const u16* __restrict__ k_s,   // [bh][l][32]
    const u16* __restrict__ vt,    // [bh][32][1024]
    u16* __restrict__ ctx)         // [bh][l][32]
{
    __shared__ u16 Ps[4][2][16 * 72];  // per-wave, per-tile P [q][key]
    int tid = threadIdx.x;
    int w = tid >> 6, lane = tid & 63, l15 = lane & 15, quad = lane >> 4;
    int g = blockIdx.x;                      // 1024 blocks = 8 qt x 128 bh
    int bh = (g & 7) | ((g >> 6) << 3);      // XCD-local bh grouping
    int q0 = ((g >> 3) & 7) * 128 + w * 32;

    const u16* kb = k_s + (size_t)bh * 1024 * 32;
    const u16* vb = vt  + (size_t)bh * 32 * 1024;

    F4U qf[2];   // B-frags: lane holds Q[q=l15][d=quad*8+j] for both tiles
    qf[0].u = *(const uint4*)(q_s + ((size_t)bh * 1024 + q0 + l15) * 32 + quad * 8);
    qf[1].u = *(const uint4*)(q_s + ((size_t)bh * 1024 + q0 + 16 + l15) * 32 + quad * 8);

    f4_t O[2][2] = {{{0,0,0,0},{0,0,0,0}},{{0,0,0,0},{0,0,0,0}}};
    float psum[2] = {0.f, 0.f};

    F4U kA[4], kB[4];

    auto LDK = [&](F4U* k, int key0) {
        #pragma unroll
        for (int nt = 0; nt < 4; ++nt)
            k[nt].u = *(const uint4*)(kb + (size_t)(key0 + nt * 16 + l15) * 32 + quad * 8);
    };
    auto STEP = [&](F4U* k, int key0) {
        F4U v[4];   // V loads first; consumed after both tiles' softmax
        v[0].u = *(const uint4*)(vb + (size_t)l15 * 1024 + key0 + quad * 8);
        v[1].u = *(const uint4*)(vb + (size_t)(16 + l15) * 1024 + key0 + quad * 8);
        v[2].u = *(const uint4*)(vb + (size_t)l15 * 1024 + key0 + 32 + quad * 8);
        v[3].u = *(const uint4*)(vb + (size_t)(16 + l15) * 1024 + key0 + 32 + quad * 8);
        #pragma unroll
        for (int t = 0; t < 2; ++t) {
            f4_t s[4];
            #pragma unroll
            for (int nt = 0; nt < 4; ++nt) {
                f4_t z = {0,0,0,0};
                s[nt] = __builtin_amdgcn_mfma_f32_16x16x32_bf16(k[nt].s, qf[t].s, z, 0, 0, 0);
            }
            u16* psw = Ps[w][t];
            #pragma unroll
            for (int nt = 0; nt < 4; ++nt) {
                float p0 = exp2f(s[nt][0]), p1 = exp2f(s[nt][1]);
                float p2 = exp2f(s[nt][2]), p3 = exp2f(s[nt][3]);
                psum[t] += (p0 + p1) + (p2 + p3);
                uint2 pk = { pack2t(p0, p1), pack2t(p2, p3) };
                *(uint2*)(psw + l15 * 72 + nt * 16 + quad * 4) = pk;
            }
        }
        #pragma unroll
        for (int t = 0; t < 2; ++t) {
            u16* psw = Ps[w][t];
            #pragma unroll
            for (int k2 = 0; k2 < 2; ++k2) {
                F4U pf; pf.u = *(const uint4*)(psw + l15 * 72 + k2 * 32 + quad * 8);
                O[t][0] = __builtin_amdgcn_mfma_f32_16x16x32_bf16(v[k2 * 2 + 0].s, pf.s, O[t][0], 0, 0, 0);
                O[t][1] = __builtin_amdgcn_mfma_f32_16x16x32_bf16(v[k2 * 2 + 1].s, pf.s, O[t][1], 0, 0, 0);
            }
        }
    };

    LDK(kA, 0);
    for (int c = 0; c < 16; c += 2) {
        LDK(kB, (c + 1) * 64);
        STEP(kA, c * 64);
        if (c + 2 < 16) LDK(kA, (c + 2) * 64);
        STEP(kB, (c + 1) * 64);
    }

    #pragma unroll
    for (int t = 0; t < 2; ++t) {
        float ps = psum[t];
        ps += __shfl_xor(ps, 16);
        ps += __shfl_xor(ps, 32);
        float inv = 1.0f / ps;
        // O C-layout is [d=quad*4+r][q=l15]: pack 4 d's -> 8B stores
        u16* op = ctx + ((size_t)bh * 1024 + q0 + t * 16 + l15) * 32;
        uint2 s0, s1;
        s0.x = pack2(O[t][0][0] * inv, O[t][0][1] * inv);
        s0.y = pack2(O[t][0][2] * inv, O[t][0][3] * inv);
        s1.x = pack2(O[t][1][0] * inv, O[t][1][1] * inv);
        s1.y = pack2(O[t][1][2] * inv, O[t][1][3] * inv);
        *(uint2*)(op + quad * 4)      = s0;
        *(uint2*)(op + 16 + quad * 4) = s1;
    }
}

// ---- kernel 4: out = LN(ctx @ Wout^T + out_b + emb) -> fp32, fused.
// 512 blocks x 32 rows; wave (wr,wc): rows wr*16, cols wc*128 (8 nc frags).
// Transposed C: each lane owns one token row's 32 cols; LN = 2 shfl_xor +
// tiny LDS exchange between the two col-half waves.
__global__ __launch_bounds__(256) void proj_ln_k(
    const u16* __restrict__ ctx,      // [bh][l][32] bf16
    const u16* __restrict__ wout,     // [256,256] bf16
    const float* __restrict__ out_b,  // [256]
    const u16* __restrict__ emb,      // [M,256] bf16
    float* __restrict__ out)          // [M,256] fp32
{
    __shared__ float2 sm[2][2][16];   // [wr][wc][l15]
    int tid = threadIdx.x;
    int w = tid >> 6, lane = tid & 63, l15 = lane & 15, quad = lane >> 4;
    int wr = w >> 1, wc = w & 1;
    int m0 = blockIdx.x * 32;
    int b = m0 >> 10, lbase = (m0 & 1023) + wr * 16 + l15;

    const u16* Bp = wout + (size_t)(wc * 128 + l15) * 256 + quad * 8;

    f4_t acc[8];
    #pragma unroll
    for (int nc = 0; nc < 8; ++nc) acc[nc] = (f4_t){0,0,0,0};

    #pragma unroll
    for (int ks = 0; ks < 8; ++ks) {      // k = ks*32 + quad*8+j (head ks)
        F4U a; a.u = *(const uint4*)(ctx + ((size_t)(b * 8 + ks) * 1024 + lbase) * 32 + quad * 8);
        #pragma unroll
        for (int nc = 0; nc < 8; ++nc) {
            F4U bf; bf.u = *(const uint4*)(Bp + (size_t)nc * 16 * 256 + ks * 32);
            acc[nc] = __builtin_amdgcn_mfma_f32_16x16x32_bf16(bf.s, a.s, acc[nc], 0, 0, 0);
        }
    }

    int row = m0 + wr * 16 + l15;
    float s = 0.f, q = 0.f;
    #pragma unroll
    for (int nc = 0; nc < 8; ++nc) {
        int nb = wc * 128 + nc * 16 + quad * 4;
        float4 bb = *(const float4*)(out_b + nb);
        ushort4 e4 = *(const ushort4*)(emb + (size_t)row * 256 + nb);
        acc[nc][0] += bb.x + bf2f(e4.x);
        acc[nc][1] += bb.y + bf2f(e4.y);
        acc[nc][2] += bb.z + bf2f(e4.z);
        acc[nc][3] += bb.w + bf2f(e4.w);
        #pragma unroll
        for (int r = 0; r < 4; ++r) { s += acc[nc][r]; q += acc[nc][r] * acc[nc][r]; }
    }
    s += __shfl_xor(s, 16);  q += __shfl_xor(q, 16);
    s += __shfl_xor(s, 32);  q += __shfl_xor(q, 32);
    if (quad == 0) sm[wr][wc][l15] = make_float2(s, q);
    __syncthreads();
    float2 oth = sm[wr][1 - wc][l15];
    s += oth.x; q += oth.y;
    float mean = s * (1.0f / 256.0f);
    float var  = q * (1.0f / 256.0f) - mean * mean;
    float rstd = rsqrtf(var + 1e-5f);
    #pragma unroll
    for (int nc = 0; nc < 8; ++nc) {
        float4 o = { (acc[nc][0] - mean) * rstd, (acc[nc][1] - mean) * rstd,
                     (acc[nc][2] - mean) * rstd, (acc[nc][3] - mean) * rstd };
        *(float4*)(out + (size_t)row * 256 + wc * 128 + nc * 16 + quad * 4) = o;
    }
}

extern "C" void kernel_launch(void* const* d_in, const int* in_sizes, int n_in,
                              void* d_out, int out_size, void* d_ws, size_t ws_size,
                              hipStream_t stream) {
    const int*   seq       = (const int*)d_in[0];
    const float* emb_w     = (const float*)d_in[1];
    const float* emb_b     = (const float*)d_in[2];
    const float* in_proj_w = (const float*)d_in[3];
    const float* in_proj_b = (const float*)d_in[4];
    const float* out_w     = (const float*)d_in[5];
    const float* out_b     = (const float*)d_in[6];
    float*       out       = (float*)d_out;

    const size_t P = (size_t)M_ * 256;
    u16* ws   = (u16*)d_ws;
    u16* emb  = ws;                 //  8 MB [M,256]
    u16* q_s  = ws + P;             //  8 MB [bh][l][32]
    u16* k_s  = ws + 2 * P;         //  8 MB [bh][l][32]
    u16* vt   = ws + 3 * P;         //  8 MB [bh][32][1024]
    u16* ctx  = ws + 4 * P;         //  8 MB [bh][l][32]
    u16* wqkv = ws + 5 * P;         //  384 KB [768,256] bf16
    u16* wout = wqkv + 768 * 256;   //  128 KB [256,256] bf16

    embed_conv_k<<<M_ / 4, 256, 0, stream>>>(seq, emb_w, emb_b, in_proj_w, out_w, emb, wqkv);
    gemm_qkv_mfma_k<<<dim3(12, 128), 256, 0, stream>>>(emb, wqkv, in_proj_b, q_s, k_s, vt);
    attn2_k<<<1024, 256, 0, stream>>>(q_s, k_s, vt, ctx);
    proj_ln_k<<<M_ / 32, 256, 0, stream>>>(ctx, wout, out_b, emb, out);
}

// Round 12
// 187.106 us; speedup vs baseline: 1.4133x; 1.0646x over previous
//
#include <hip/hip_runtime.h>

#define B_  16
#define L_  1024
#define E_  256
#define H_  8
#define DH_ 32
#define M_  (B_ * L_)                 // 16384 rows
#define SCALE_L2E 0.25501817656f      // (1/sqrt(32)) * log2(e)

typedef unsigned short u16;
typedef unsigned int   u32;
typedef short bf8_t __attribute__((ext_vector_type(8)));   // 8 bf16 (4 VGPRs)
typedef float f4_t  __attribute__((ext_vector_type(4)));   // MFMA acc
union F4U { uint4 u; bf8_t s; };

static __device__ __forceinline__ float bf2f(u16 u) {
    return __uint_as_float(((u32)u) << 16);
}
static __device__ __forceinline__ u16 f2bf(float f) {
    u32 u = __float_as_uint(f);
    u32 r = 0x7FFFu + ((u >> 16) & 1u);   // RNE
    return (u16)((u + r) >> 16);
}
static __device__ __forceinline__ u32 pack2(float a, float b) {
    return (u32)f2bf(a) | ((u32)f2bf(b) << 16);
}
// truncated bf16 pair pack: 2 VALU ops (P values only; psum stays exact fp32)
static __device__ __forceinline__ u32 pack2t(float a, float b) {
    return (__float_as_uint(a) >> 16) | (__float_as_uint(b) & 0xFFFF0000u);
}

// ---- kernel 1: embedding gather + LN (wave-per-row); low blocks convert W->bf16
__global__ __launch_bounds__(256) void embed_conv_k(
    const int* __restrict__ seq,
    const float* __restrict__ emb_w,      // [L,E,4] fp32 (read as float4)
    const float* __restrict__ emb_b,      // [L,E]
    const float* __restrict__ in_proj_w,  // [768,256] fp32
    const float* __restrict__ out_w,      // [256,256] fp32
    u16* __restrict__ emb,                // [M,256] bf16
    u16* __restrict__ wcvt)               // [768*256 + 256*256] bf16 (wqkv|wout)
{
    int blk = blockIdx.x, tid = threadIdx.x;
    if (blk < 1024) {                      // 262144 weight elements
        int idx = blk * 256 + tid;
        float v = (idx < 196608) ? in_proj_w[idx] : out_w[idx - 196608];
        wcvt[idx] = f2bf(v);
    }
    int w = tid >> 6, lane = tid & 63;
    int bl = blk * 4 + w;                  // row in [0, M)
    int l = bl & (L_ - 1);
    int cls = seq[bl];
    const float4* wrow = (const float4*)emb_w + (size_t)l * 256;
    float4 bb = *(const float4*)(emb_b + (size_t)l * 256 + lane * 4);
    float bv[4] = {bb.x, bb.y, bb.z, bb.w};
    float x[4], s = 0.f, q = 0.f;
    #pragma unroll
    for (int j = 0; j < 4; ++j) {
        float4 w4 = wrow[lane * 4 + j];
        float t = ((cls == 0) ? w4.x : (cls == 1) ? w4.y : (cls == 2) ? w4.z : w4.w) + bv[j];
        x[j] = t; s += t; q += t * t;
    }
    #pragma unroll
    for (int off = 1; off < 64; off <<= 1) {
        s += __shfl_xor(s, off);
        q += __shfl_xor(q, off);
    }
    float mean = s * (1.0f / 256.0f);
    float var  = q * (1.0f / 256.0f) - mean * mean;
    float rstd = rsqrtf(var + 1e-5f);
    ushort4 o = { f2bf((x[0] - mean) * rstd), f2bf((x[1] - mean) * rstd),
                  f2bf((x[2] - mean) * rstd), f2bf((x[3] - mean) * rstd) };
    *(ushort4*)(emb + (size_t)bl * 256 + lane * 4) = o;
}

// ---- kernel 2: QKV = emb @ Wqkv^T + b (MFMA, LDS-free), 4 m-tiles per wave
// (B-frags reused 4x -> 8 loads feed 16 MFMAs per ks). Q/K: transposed C ->
// ushort4 stores into [bh][l][32]; V: normal C, stored transposed vt[bh][d][l].
__global__ __launch_bounds__(256) void gemm_qkv_mfma_k(
    const u16* __restrict__ emb,      // [M,256] bf16
    const u16* __restrict__ wqkv,     // [768,256] bf16
    const float* __restrict__ bias,   // [768] fp32
    u16* __restrict__ q_s, u16* __restrict__ k_s, u16* __restrict__ vt)
{
    int tid = threadIdx.x;
    int w = tid >> 6, lane = tid & 63, l15 = lane & 15, quad = lane >> 4;
    int n0 = blockIdx.x * 64, m0 = blockIdx.y * 256;
    int b = m0 >> 10;

    const u16* Ap = emb  + (size_t)(m0 + w * 64 + l15) * 256 + quad * 8;
    const u16* Bp = wqkv + (size_t)(n0 + l15) * 256 + quad * 8;

    f4_t acc[4][4] = {{{0,0,0,0},{0,0,0,0},{0,0,0,0},{0,0,0,0}},
                      {{0,0,0,0},{0,0,0,0},{0,0,0,0},{0,0,0,0}},
                      {{0,0,0,0},{0,0,0,0},{0,0,0,0},{0,0,0,0}},
                      {{0,0,0,0},{0,0,0,0},{0,0,0,0},{0,0,0,0}}};

    if (n0 < 512) {                        // ---- Q or K: transposed C ----
        #pragma unroll
        for (int ks = 0; ks < 8; ++ks) {
            F4U bfr[4];
            #pragma unroll
            for (int nc = 0; nc < 4; ++nc)
                bfr[nc].u = *(const uint4*)(Bp + nc * 16 * 256 + ks * 32);
            #pragma unroll
            for (int t = 0; t < 4; ++t) {
                F4U a; a.u = *(const uint4*)(Ap + t * 16 * 256 + ks * 32);
                #pragma unroll
                for (int nc = 0; nc < 4; ++nc)
                    acc[t][nc] = __builtin_amdgcn_mfma_f32_16x16x32_bf16(bfr[nc].s, a.s, acc[t][nc], 0, 0, 0);
            }
        }
        float sc = (n0 < 256) ? SCALE_L2E : 1.0f;
        u16* dst = (n0 < 256) ? q_s : k_s;
        #pragma unroll
        for (int t = 0; t < 4; ++t) {
            int l = (m0 & 1023) + w * 64 + t * 16 + l15;
            #pragma unroll
            for (int nc = 0; nc < 4; ++nc) {
                int nb = n0 + nc * 16 + quad * 4;  // 4 consecutive n = same head
                float4 b4 = *(const float4*)(bias + nb);
                int nl = nb & 255, h = nl >> 5, d0 = nl & 31;
                ushort4 o = { f2bf((acc[t][nc][0] + b4.x) * sc), f2bf((acc[t][nc][1] + b4.y) * sc),
                              f2bf((acc[t][nc][2] + b4.z) * sc), f2bf((acc[t][nc][3] + b4.w) * sc) };
                *(ushort4*)(dst + ((size_t)(b * 8 + h) * 1024 + l) * 32 + d0) = o;
            }
        }
    } else {                               // ---- V: normal C, store transposed ----
        #pragma unroll
        for (int ks = 0; ks < 8; ++ks) {
            F4U bfr[4];
            #pragma unroll
            for (int nc = 0; nc < 4; ++nc)
                bfr[nc].u = *(const uint4*)(Bp + nc * 16 * 256 + ks * 32);
            #pragma unroll
            for (int t = 0; t < 4; ++t) {
                F4U a; a.u = *(const uint4*)(Ap + t * 16 * 256 + ks * 32);
                #pragma unroll
                for (int nc = 0; nc < 4; ++nc)
                    acc[t][nc] = __builtin_amdgcn_mfma_f32_16x16x32_bf16(a.s, bfr[nc].s, acc[t][nc], 0, 0, 0);
            }
        }
        #pragma unroll
        for (int t = 0; t < 4; ++t) {
            int lq = (m0 & 1023) + w * 64 + t * 16 + quad * 4;
            #pragma unroll
            for (int nc = 0; nc < 4; ++nc) {
                int n = n0 + nc * 16 + l15;
                float bv = bias[n];
                int nl = n & 255, h = nl >> 5, d = nl & 31;
                ushort4 o = { f2bf(acc[t][nc][0] + bv), f2bf(acc[t][nc][1] + bv),
                              f2bf(acc[t][nc][2] + bv), f2bf(acc[t][nc][3] + bv) };
                *(ushort4*)(vt + ((size_t)(b * 8 + h) * 32 + d) * 1024 + lq) = o;
            }
        }
    }
}

// ---- kernel 3: MFMA flash attention. 64 q-rows per wave (4 q-tiles share all
// K/V fragments -> 4x arithmetic intensity vs R10). XCD-swizzled: all 4 blocks
// of a bh share g%8 (2 MB K/V per XCD L2). K ping-pong; fixed-max softmax.
__global__ __launch_bounds__(256) void attn2_k(
    const u16* __restrict__ q_s,   // [bh][l][32] (pre-scaled by SCALE*log2e)
    const u16* __restrict__ k_s,   // [bh][l][32]
    const u16* __restrict__ vt,    // [bh][32][1024]
    u16* __restrict__ ctx)         // [bh][l][32]
{
    __shared__ u16 Ps[4][4][16 * 72];  // per-wave, per-tile P [q][key] (36 KB)
    int tid = threadIdx.x;
    int w = tid >> 6, lane = tid & 63, l15 = lane & 15, quad = lane >> 4;
    int g = blockIdx.x;                      // 512 blocks = 4 qt x 128 bh
    int bh = (g & 7) | ((g >> 5) << 3);      // XCD-local bh grouping
    int q0 = ((g >> 3) & 3) * 256 + w * 64;

    const u16* kb = k_s + (size_t)bh * 1024 * 32;
    const u16* vb = vt  + (size_t)bh * 32 * 1024;

    F4U qf[4];   // B-frags: lane holds Q[q=l15][d=quad*8+j] for 4 tiles
    #pragma unroll
    for (int t = 0; t < 4; ++t)
        qf[t].u = *(const uint4*)(q_s + ((size_t)bh * 1024 + q0 + t * 16 + l15) * 32 + quad * 8);

    f4_t O[4][2] = {{{0,0,0,0},{0,0,0,0}},{{0,0,0,0},{0,0,0,0}},
                    {{0,0,0,0},{0,0,0,0}},{{0,0,0,0},{0,0,0,0}}};
    float psum[4] = {0.f, 0.f, 0.f, 0.f};

    F4U kA[4], kB[4];

    auto LDK = [&](F4U* k, int key0) {
        #pragma unroll
        for (int nt = 0; nt < 4; ++nt)
            k[nt].u = *(const uint4*)(kb + (size_t)(key0 + nt * 16 + l15) * 32 + quad * 8);
    };
    auto STEP = [&](F4U* k, int key0) {
        F4U v[4];   // V loads first; consumed after all 4 tiles' softmax
        v[0].u = *(const uint4*)(vb + (size_t)l15 * 1024 + key0 + quad * 8);
        v[1].u = *(const uint4*)(vb + (size_t)(16 + l15) * 1024 + key0 + quad * 8);
        v[2].u = *(const uint4*)(vb + (size_t)l15 * 1024 + key0 + 32 + quad * 8);
        v[3].u = *(const uint4*)(vb + (size_t)(16 + l15) * 1024 + key0 + 32 + quad * 8);
        #pragma unroll
        for (int t = 0; t < 4; ++t) {
            f4_t s[4];
            #pragma unroll
            for (int nt = 0; nt < 4; ++nt) {
                f4_t z = {0,0,0,0};
                s[nt] = __builtin_amdgcn_mfma_f32_16x16x32_bf16(k[nt].s, qf[t].s, z, 0, 0, 0);
            }
            u16* psw = Ps[w][t];
            #pragma unroll
            for (int nt = 0; nt < 4; ++nt) {
                float p0 = exp2f(s[nt][0]), p1 = exp2f(s[nt][1]);
                float p2 = exp2f(s[nt][2]), p3 = exp2f(s[nt][3]);
                psum[t] += (p0 + p1) + (p2 + p3);
                uint2 pk = { pack2t(p0, p1), pack2t(p2, p3) };
                *(uint2*)(psw + l15 * 72 + nt * 16 + quad * 4) = pk;
            }
        }
        #pragma unroll
        for (int t = 0; t < 4; ++t) {
            u16* psw = Ps[w][t];
            #pragma unroll
            for (int k2 = 0; k2 < 2; ++k2) {
                F4U pf; pf.u = *(const uint4*)(psw + l15 * 72 + k2 * 32 + quad * 8);
                O[t][0] = __builtin_amdgcn_mfma_f32_16x16x32_bf16(v[k2 * 2 + 0].s, pf.s, O[t][0], 0, 0, 0);
                O[t][1] = __builtin_amdgcn_mfma_f32_16x16x32_bf16(v[k2 * 2 + 1].s, pf.s, O[t][1], 0, 0, 0);
            }
        }
    };

    LDK(kA, 0);
    for (int c = 0; c < 16; c += 2) {
        LDK(kB, (c + 1) * 64);
        STEP(kA, c * 64);
        if (c + 2 < 16) LDK(kA, (c + 2) * 64);
        STEP(kB, (c + 1) * 64);
    }

    #pragma unroll
    for (int t = 0; t < 4; ++t) {
        float ps = psum[t];
        ps += __shfl_xor(ps, 16);
        ps += __shfl_xor(ps, 32);
        float inv = 1.0f / ps;
        // O C-layout is [d=quad*4+r][q=l15]: pack 4 d's -> 8B stores
        u16* op = ctx + ((size_t)bh * 1024 + q0 + t * 16 + l15) * 32;
        uint2 s0, s1;
        s0.x = pack2(O[t][0][0] * inv, O[t][0][1] * inv);
        s0.y = pack2(O[t][0][2] * inv, O[t][0][3] * inv);
        s1.x = pack2(O[t][1][0] * inv, O[t][1][1] * inv);
        s1.y = pack2(O[t][1][2] * inv, O[t][1][3] * inv);
        *(uint2*)(op + quad * 4)      = s0;
        *(uint2*)(op + 16 + quad * 4) = s1;
    }
}

// ---- kernel 4: out = LN(ctx @ Wout^T + out_b + emb) -> fp32, fused.
// 256 blocks x 64 rows; wave (wr,wc): 2 row-tiles (rows wr*32 + t*16), cols
// wc*128 (8 nc frags shared across both tiles -> weight traffic halved).
// LN = 2 shfl_xor + LDS exchange between the two col-half waves.
__global__ __launch_bounds__(256) void proj_ln_k(
    const u16* __restrict__ ctx,      // [bh][l][32] bf16
    const u16* __restrict__ wout,     // [256,256] bf16
    const float* __restrict__ out_b,  // [256]
    const u16* __restrict__ emb,      // [M,256] bf16
    float* __restrict__ out)          // [M,256] fp32
{
    __shared__ float2 sm[4][2][16];   // [wr*2+t][wc][l15]
    int tid = threadIdx.x;
    int w = tid >> 6, lane = tid & 63, l15 = lane & 15, quad = lane >> 4;
    int wr = w >> 1, wc = w & 1;
    int m0 = blockIdx.x * 64;
    int b = m0 >> 10;

    const u16* Bp = wout + (size_t)(wc * 128 + l15) * 256 + quad * 8;

    f4_t acc[2][8];
    #pragma unroll
    for (int t = 0; t < 2; ++t)
        #pragma unroll
        for (int nc = 0; nc < 8; ++nc) acc[t][nc] = (f4_t){0,0,0,0};

    #pragma unroll
    for (int ks = 0; ks < 8; ++ks) {      // k = ks*32 + quad*8+j (head ks)
        F4U bfr[8];
        #pragma unroll
        for (int nc = 0; nc < 8; ++nc)
            bfr[nc].u = *(const uint4*)(Bp + (size_t)nc * 16 * 256 + ks * 32);
        #pragma unroll
        for (int t = 0; t < 2; ++t) {
            int lb = (m0 & 1023) + wr * 32 + t * 16 + l15;
            F4U a; a.u = *(const uint4*)(ctx + ((size_t)(b * 8 + ks) * 1024 + lb) * 32 + quad * 8);
            #pragma unroll
            for (int nc = 0; nc < 8; ++nc)
                acc[t][nc] = __builtin_amdgcn_mfma_f32_16x16x32_bf16(bfr[nc].s, a.s, acc[t][nc], 0, 0, 0);
        }
    }

    float sv[2], qv[2];
    #pragma unroll
    for (int t = 0; t < 2; ++t) {
        int row = m0 + wr * 32 + t * 16 + l15;
        float s = 0.f, q = 0.f;
        #pragma unroll
        for (int nc = 0; nc < 8; ++nc) {
            int nb = wc * 128 + nc * 16 + quad * 4;
            float4 bb = *(const float4*)(out_b + nb);
            ushort4 e4 = *(const ushort4*)(emb + (size_t)row * 256 + nb);
            acc[t][nc][0] += bb.x + bf2f(e4.x);
            acc[t][nc][1] += bb.y + bf2f(e4.y);
            acc[t][nc][2] += bb.z + bf2f(e4.z);
            acc[t][nc][3] += bb.w + bf2f(e4.w);
            #pragma unroll
            for (int r = 0; r < 4; ++r) { s += acc[t][nc][r]; q += acc[t][nc][r] * acc[t][nc][r]; }
        }
        s += __shfl_xor(s, 16);  q += __shfl_xor(q, 16);
        s += __shfl_xor(s, 32);  q += __shfl_xor(q, 32);
        sv[t] = s; qv[t] = q;
        if (quad == 0) sm[wr * 2 + t][wc][l15] = make_float2(s, q);
    }
    __syncthreads();
    #pragma unroll
    for (int t = 0; t < 2; ++t) {
        int row = m0 + wr * 32 + t * 16 + l15;
        float2 oth = sm[wr * 2 + t][1 - wc][l15];
        float s = sv[t] + oth.x, q = qv[t] + oth.y;
        float mean = s * (1.0f / 256.0f);
        float var  = q * (1.0f / 256.0f) - mean * mean;
        float rstd = rsqrtf(var + 1e-5f);
        #pragma unroll
        for (int nc = 0; nc < 8; ++nc) {
            float4 o = { (acc[t][nc][0] - mean) * rstd, (acc[t][nc][1] - mean) * rstd,
                         (acc[t][nc][2] - mean) * rstd, (acc[t][nc][3] - mean) * rstd };
            *(float4*)(out + (size_t)row * 256 + wc * 128 + nc * 16 + quad * 4) = o;
        }
    }
}

extern "C" void kernel_launch(void* const* d_in, const int* in_sizes, int n_in,
                              void* d_out, int out_size, void* d_ws, size_t ws_size,
                              hipStream_t stream) {
    const int*   seq       = (const int*)d_in[0];
    const float* emb_w     = (const float*)d_in[1];
    const float* emb_b     = (const float*)d_in[2];
    const float* in_proj_w = (const float*)d_in[3];
    const float* in_proj_b = (const float*)d_in[4];
    const float* out_w     = (const float*)d_in[5];
    const float* out_b     = (const float*)d_in[6];
    float*       out       = (float*)d_out;

    const size_t P = (size_t)M_ * 256;
    u16* ws   = (u16*)d_ws;
    u16* emb  = ws;                 //  8 MB [M,256]
    u16* q_s  = ws + P;             //  8 MB [bh][l][32]
    u16* k_s  = ws + 2 * P;         //  8 MB [bh][l][32]
    u16* vt   = ws + 3 * P;         //  8 MB [bh][32][1024]
    u16* ctx  = ws + 4 * P;         //  8 MB [bh][l][32]
    u16* wqkv = ws + 5 * P;         //  384 KB [768,256] bf16
    u16* wout = wqkv + 768 * 256;   //  128 KB [256,256] bf16

    embed_conv_k<<<M_ / 4, 256, 0, stream>>>(seq, emb_w, emb_b, in_proj_w, out_w, emb, wqkv);
    gemm_qkv_mfma_k<<<dim3(12, 64), 256, 0, stream>>>(emb, wqkv, in_proj_b, q_s, k_s, vt);
    attn2_k<<<512, 256, 0, stream>>>(q_s, k_s, vt, ctx);
    proj_ln_k<<<M_ / 64, 256, 0, stream>>>(ctx, wout, out_b, emb, out);
}